// Round 3
// baseline (1300.544 us; speedup 1.0000x reference)
//
#include <hip/hip_runtime.h>

// ---------------------------------------------------------------------------
// BiGRU + concept-attention + CNN classifier forward, MI355X gfx950.
// B=64 T=128 D=300 H=256 V=30000 K=16, filters 3/4/5 x100, CLS=5.
// Round 3: inputs are f32 on device (round-2 evidence: detection routed f32
// path; plausible partial output). Output is FLOAT32 (round-2 absmax 0.2275 =
// "second half of f32 buffer zero" signature). Internally bf16 for MFMA.
// ---------------------------------------------------------------------------

typedef unsigned short u16;
typedef unsigned int u32;
typedef __attribute__((ext_vector_type(4))) u16 u16x4;
typedef __attribute__((ext_vector_type(8))) u16 u16x8;
typedef __attribute__((ext_vector_type(8))) __bf16 bf16x8;
typedef __attribute__((ext_vector_type(4))) float f32x4;

__device__ __forceinline__ float bf2f(u16 u) {
    union { u32 i; float f; } x; x.i = ((u32)u) << 16; return x.f;
}
__device__ __forceinline__ u16 f2bf(float f) {
    union { float f; u32 i; } x; x.f = f;
    u32 r = x.i + 0x7FFFu + ((x.i >> 16) & 1u);  // RNE
    return (u16)(r >> 16);
}
__device__ __forceinline__ float sigm(float x) { return 1.f / (1.f + __expf(-x)); }
__device__ __forceinline__ float tanh_(float x) {
    float e = __expf(-2.f * fabsf(x));
    float t = (1.f - e) / (1.f + e);
    return x < 0.f ? -t : t;
}

// ---------------------------------------------------------------------------
// detect_k: flags[0]=1 if float tensors are f32 (else bf16);
//           flags[1]=1 if concept_mask is byte-packed (else int32).
// ---------------------------------------------------------------------------
__global__ __launch_bounds__(256) void detect_k(
    const u32* __restrict__ emb_raw, const u32* __restrict__ cmask_raw,
    int* __restrict__ flags)
{
    __shared__ int cnt0, cnt1;
    if (threadIdx.x == 0) { cnt0 = 0; cnt1 = 0; }
    __syncthreads();
    int c0 = 0;
    for (int i = threadIdx.x; i < 4096; i += 256) {
        float lo = bf2f((u16)(emb_raw[i] & 0xFFFFu));
        if (!(fabsf(lo) <= 4.0f)) c0++;   // catches big and NaN
    }
    int c1 = 0;
    for (int i = threadIdx.x; i < 1024; i += 256) {
        if (cmask_raw[i] > 1u) c1++;      // int32 bools are only 0 or 1
    }
    if (c0) atomicAdd(&cnt0, c0);
    if (c1) atomicAdd(&cnt1, c1);
    __syncthreads();
    if (threadIdx.x == 0) {
        flags[0] = (cnt0 > 64) ? 1 : 0;
        flags[1] = (cnt1 > 0) ? 1 : 0;
    }
}

// ---------------------------------------------------------------------------
// convert_many: round (f32 mode) or copy (bf16 mode) float buffers into ws.
// ---------------------------------------------------------------------------
struct CvtDesc { const void* src; u16* dst; int n; };
struct CvtArgs { CvtDesc d[20]; };

__global__ __launch_bounds__(256) void convert_many(CvtArgs a, const int* __restrict__ flags)
{
    CvtDesc de = a.d[blockIdx.y];
    const bool f32m = flags[0] != 0;
    int i4 = (blockIdx.x * 256 + threadIdx.x) * 4;
    if (i4 >= de.n) return;
    if (i4 + 4 <= de.n) {
        if (f32m) {
            const float* s = (const float*)de.src + i4;
            u16x4 o; o[0] = f2bf(s[0]); o[1] = f2bf(s[1]); o[2] = f2bf(s[2]); o[3] = f2bf(s[3]);
            *(u16x4*)(de.dst + i4) = o;
        } else {
            *(u16x4*)(de.dst + i4) = *(const u16x4*)((const u16*)de.src + i4);
        }
    } else {
        for (int e = 0; e < 4 && i4 + e < de.n; ++e)
            de.dst[i4 + e] = f32m ? f2bf(((const float*)de.src)[i4 + e])
                                  : ((const u16*)de.src)[i4 + e];
    }
}

// ---------------------------------------------------------------------------
// build_mask: concept_mask (either storage) -> 16-bit validity mask per v.
// ---------------------------------------------------------------------------
__global__ __launch_bounds__(256) void build_mask(
    const void* __restrict__ cmask, int* __restrict__ mask16, const int* __restrict__ flags)
{
    int v = blockIdx.x * 256 + threadIdx.x;
    if (v >= 30000) return;
    int m = 0;
    if (flags[1]) {
        const unsigned char* p = (const unsigned char*)cmask + (size_t)v * 16;
#pragma unroll
        for (int k = 0; k < 16; ++k) if (p[k]) m |= (1 << k);
    } else {
        const int* p = (const int*)cmask + (size_t)v * 16;
#pragma unroll
        for (int k = 0; k < 16; ++k) if (p[k]) m |= (1 << k);
    }
    mask16[v] = m;
}

// ---------------------------------------------------------------------------
// Generic MFMA GEMM: C[M,N] = A[M,K](bf16) * W[N,K]^T(bf16) + bias, opt ReLU.
// ROWMODE 0: A row m at A + m*lda
// ROWMODE 1: A row m at A + rowidx[m]*lda            (embedding gather)
// ROWMODE 2: A row m=(b*L+l) at A + (b*strideT+l)*lda (conv window view)
// EPI: 1 = +bias, 2 = +bias,ReLU.  OUTBF: 1 = bf16 out, 0 = f32 out.
// Tile 64x64, BK=32, 4 waves, each wave 32x32 via 2x2 MFMA 16x16x32 frags.
// ---------------------------------------------------------------------------
template<int ROWMODE, int EPI, int OUTBF>
__global__ __launch_bounds__(256) void gemm_bt(
    const u16* __restrict__ A, const u16* __restrict__ W,
    const u16* __restrict__ bias, const int* __restrict__ rowidx,
    float* __restrict__ Cf, u16* __restrict__ Cb,
    int M, int N, int K, int lda, int ldc, int Lrows, int strideT)
{
    __shared__ __align__(16) u16 sA[64 * 40];   // +8 pad: bank-conflict relief
    __shared__ __align__(16) u16 sW[64 * 40];

    const int tid = threadIdx.x;
    const int m0 = blockIdx.y * 64;
    const int n0 = blockIdx.x * 64;

    const int l  = tid & 63;
    const int w  = tid >> 6;
    const int wm = (w >> 1) << 5;
    const int wn = (w & 1) << 5;
    const int fr = l & 15;
    const int fk = (l >> 4) << 3;

    const int sr = tid >> 2;
    const int cb = (tid & 3) << 3;

    size_t abase;
    {
        int m = m0 + sr;
        if constexpr (ROWMODE == 1) {
            abase = (size_t)rowidx[m] * (size_t)lda;
        } else if constexpr (ROWMODE == 2) {
            int b = m / Lrows; int li = m - b * Lrows;
            abase = (size_t)(b * strideT + li) * (size_t)lda;
        } else {
            abase = (size_t)m * (size_t)lda;
        }
    }
    const int  wrow   = n0 + sr;
    const bool wvalid = wrow < N;
    const size_t wbase = (size_t)wrow * (size_t)K;

    f32x4 acc00 = {0,0,0,0}, acc01 = {0,0,0,0}, acc10 = {0,0,0,0}, acc11 = {0,0,0,0};

    for (int k0 = 0; k0 < K; k0 += 32) {
        __syncthreads();
        {   // stage A tile [64 x 32]
            u16x4 v0 = {0,0,0,0}, v1 = {0,0,0,0};
            int k = k0 + cb;
            if (k + 8 <= K) {
                const u16* p = A + abase + k;
                v0 = *(const u16x4*)p;
                v1 = *(const u16x4*)(p + 4);
            } else {
#pragma unroll
                for (int e = 0; e < 4; ++e) { int kk = k + e;     if (kk < K) v0[e] = A[abase + kk]; }
#pragma unroll
                for (int e = 0; e < 4; ++e) { int kk = k + 4 + e; if (kk < K) v1[e] = A[abase + kk]; }
            }
            *(u16x4*)(sA + sr * 40 + cb)     = v0;
            *(u16x4*)(sA + sr * 40 + cb + 4) = v1;
        }
        {   // stage W tile [64 x 32]
            u16x4 v0 = {0,0,0,0}, v1 = {0,0,0,0};
            int k = k0 + cb;
            if (wvalid) {
                if (k + 8 <= K) {
                    const u16* p = W + wbase + k;
                    v0 = *(const u16x4*)p;
                    v1 = *(const u16x4*)(p + 4);
                } else {
#pragma unroll
                    for (int e = 0; e < 4; ++e) { int kk = k + e;     if (kk < K) v0[e] = W[wbase + kk]; }
#pragma unroll
                    for (int e = 0; e < 4; ++e) { int kk = k + 4 + e; if (kk < K) v1[e] = W[wbase + kk]; }
                }
            }
            *(u16x4*)(sW + sr * 40 + cb)     = v0;
            *(u16x4*)(sW + sr * 40 + cb + 4) = v1;
        }
        __syncthreads();

        bf16x8 a0 = *(const bf16x8*)(sA + (wm + fr)      * 40 + fk);
        bf16x8 a1 = *(const bf16x8*)(sA + (wm + 16 + fr) * 40 + fk);
        bf16x8 b0 = *(const bf16x8*)(sW + (wn + fr)      * 40 + fk);
        bf16x8 b1 = *(const bf16x8*)(sW + (wn + 16 + fr) * 40 + fk);

        acc00 = __builtin_amdgcn_mfma_f32_16x16x32_bf16(a0, b0, acc00, 0, 0, 0);
        acc01 = __builtin_amdgcn_mfma_f32_16x16x32_bf16(a0, b1, acc01, 0, 0, 0);
        acc10 = __builtin_amdgcn_mfma_f32_16x16x32_bf16(a1, b0, acc10, 0, 0, 0);
        acc11 = __builtin_amdgcn_mfma_f32_16x16x32_bf16(a1, b1, acc11, 0, 0, 0);
    }

    // epilogue: C/D layout col = lane&15, row = (lane>>4)*4 + reg
    const int rb = (l >> 4) << 2;
    const int cc = l & 15;
#define EPILOG(ACC, I, J)                                                     \
    {                                                                         \
        int col = n0 + wn + (J)*16 + cc;                                      \
        if (col < N) {                                                        \
            float bv = bf2f(bias[col]);                                       \
            _Pragma("unroll")                                                 \
            for (int r = 0; r < 4; ++r) {                                     \
                int row = m0 + wm + (I)*16 + rb + r;                          \
                if (row < M) {                                                \
                    float v = ACC[r] + bv;                                    \
                    if (EPI == 2) v = fmaxf(v, 0.f);                          \
                    if (OUTBF) Cb[(size_t)row * ldc + col] = f2bf(v);         \
                    else       Cf[(size_t)row * ldc + col] = v;               \
                }                                                             \
            }                                                                 \
        }                                                                     \
    }
    EPILOG(acc00, 0, 0); EPILOG(acc01, 0, 1); EPILOG(acc10, 1, 0); EPILOG(acc11, 1, 1);
#undef EPILOG
}

// ---------------------------------------------------------------------------
// Wh [768,256] -> packed: u32 at (k2*3+g)*256 + j = bf16 pair of Wh[g*256+j][2k2(+1)]
// ---------------------------------------------------------------------------
__global__ __launch_bounds__(256) void transpose_wh(
    const u16* __restrict__ Whf, const u16* __restrict__ Whb,
    u32* __restrict__ whtf, u32* __restrict__ whtb)
{
    const u16* src = blockIdx.y ? Whb : Whf;
    u32* dst = blockIdx.y ? whtb : whtf;
    int idx = blockIdx.x * 256 + threadIdx.x;          // 0..98303
    int j = idx & 255;
    int rest = idx >> 8;
    int g = rest % 3;
    int k2 = rest / 3;
    u32 lo = src[(g * 256 + j) * 256 + 2 * k2];
    u32 hi = src[(g * 256 + j) * 256 + 2 * k2 + 1];
    dst[(k2 * 3 + g) * 256 + j] = lo | (hi << 16);
}

// ---------------------------------------------------------------------------
// GRU scan. grid (64 batches, 2 dirs), block 256 (thread j = hidden unit).
// ---------------------------------------------------------------------------
__global__ __launch_bounds__(256) void gru_scan(
    const u16* __restrict__ xgf, const u16* __restrict__ xgb,
    const u32* __restrict__ whtf, const u32* __restrict__ whtb,
    const u16* __restrict__ bhf, const u16* __restrict__ bhb,
    u16* __restrict__ outb)
{
    const int b = blockIdx.x, dir = blockIdx.y;
    const int j = threadIdx.x;
    const u16* xg = dir ? xgb : xgf;
    const u32* wht = dir ? whtb : whtf;
    const u16* bh = dir ? bhb : bhf;

    __shared__ float h[2][256];
    h[0][j] = 0.f;
    const float bhr = bf2f(bh[j]), bhz = bf2f(bh[256 + j]), bhn = bf2f(bh[512 + j]);
    __syncthreads();

    int cur = 0;
    for (int s = 0; s < 128; ++s) {
        const int t = dir ? (127 - s) : s;
        const float* hc = h[cur];
        float ar = 0.f, az = 0.f, an = 0.f;
#pragma unroll 4
        for (int k2 = 0; k2 < 128; ++k2) {
            float h0 = hc[2 * k2], h1 = hc[2 * k2 + 1];
            u32 ur = wht[(k2 * 3 + 0) * 256 + j];
            u32 uz = wht[(k2 * 3 + 1) * 256 + j];
            u32 un = wht[(k2 * 3 + 2) * 256 + j];
            ar += bf2f((u16)ur) * h0 + bf2f((u16)(ur >> 16)) * h1;
            az += bf2f((u16)uz) * h0 + bf2f((u16)(uz >> 16)) * h1;
            an += bf2f((u16)un) * h0 + bf2f((u16)(un >> 16)) * h1;
        }
        const size_t xb = (size_t)(b * 128 + t) * 768;
        float r = sigm(bf2f(xg[xb + j])       + ar + bhr);
        float z = sigm(bf2f(xg[xb + 256 + j]) + az + bhz);
        float n = tanh_(bf2f(xg[xb + 512 + j]) + r * (an + bhn));
        float h2 = (1.f - z) * n + z * hc[j];
        h[cur ^ 1][j] = h2;
        outb[(size_t)(b * 128 + t) * 512 + dir * 256 + j] = f2bf(h2);
        cur ^= 1;
        __syncthreads();
    }
}

// ---------------------------------------------------------------------------
// Concept attention. One block per token. Reads ctx from feat[:,0:300],
// writes concept to feat[:,300:600]. ctab read is dtype-flag-branched.
// ---------------------------------------------------------------------------
__global__ __launch_bounds__(256) void attn_kernel(
    const int* __restrict__ inp, const void* __restrict__ ctab,
    const int* __restrict__ mask16, const int* __restrict__ flags,
    u16* __restrict__ feat)
{
    const int tok = blockIdx.x;
    const int tid = threadIdx.x;
    const int v = inp[tok];
    const bool f32m = flags[0] != 0;

    __shared__ float ctx_s[300];
    __shared__ __align__(16) u16 conc_s[16 * 300];
    __shared__ float sc_s[16];
    __shared__ float at_s[16];

    for (int d = tid; d < 300; d += 256) ctx_s[d] = bf2f(feat[(size_t)tok * 600 + d]);
    if (f32m) {
        const float4* src = (const float4*)((const float*)ctab + (size_t)v * 4800);
        for (int i = tid; i < 1200; i += 256) {
            float4 x = src[i];
            u16x4 o; o[0] = f2bf(x.x); o[1] = f2bf(x.y); o[2] = f2bf(x.z); o[3] = f2bf(x.w);
            *(u16x4*)(conc_s + i * 4) = o;
        }
    } else {
        const u16x8* src = (const u16x8*)((const u16*)ctab + (size_t)v * 4800);
        u16x8* dst = (u16x8*)conc_s;
        for (int i = tid; i < 600; i += 256) dst[i] = src[i];
    }
    __syncthreads();

    const int g = tid >> 4, ln = tid & 15;
    float s = 0.f;
    for (int d = ln; d < 300; d += 16) s += bf2f(conc_s[g * 300 + d]) * ctx_s[d];
    s += __shfl_xor(s, 1); s += __shfl_xor(s, 2); s += __shfl_xor(s, 4); s += __shfl_xor(s, 8);
    if (ln == 0) sc_s[g] = ((mask16[v] >> g) & 1) ? s : -1e30f;
    __syncthreads();

    if (tid == 0) {
        float m = -1e30f;
#pragma unroll
        for (int i = 0; i < 16; ++i) m = fmaxf(m, sc_s[i]);
        float p[16]; float den = 0.f;
#pragma unroll
        for (int i = 0; i < 16; ++i) {
            float pe = (sc_s[i] <= -1e29f) ? 0.f : __expf(sc_s[i] - m);
            p[i] = pe; den += pe;
        }
        float inv = den > 0.f ? 1.f / den : 0.f;   // no-NaN guard
#pragma unroll
        for (int i = 0; i < 16; ++i) at_s[i] = p[i] * inv;
    }
    __syncthreads();

    for (int d = tid; d < 300; d += 256) {
        float a = 0.f;
#pragma unroll
        for (int g2 = 0; g2 < 16; ++g2) a += at_s[g2] * bf2f(conc_s[g2 * 300 + d]);
        feat[(size_t)tok * 600 + 300 + d] = f2bf(a);
    }
}

// ---------------------------------------------------------------------------
__global__ __launch_bounds__(128) void maxpool_k(
    const float* __restrict__ c0, const float* __restrict__ c1,
    const float* __restrict__ c2, float* __restrict__ pool)
{
    const int b = blockIdx.x, which = blockIdx.y, f = threadIdx.x;
    if (f >= 100) return;
    const float* c = which == 0 ? c0 : (which == 1 ? c1 : c2);
    const int L = which == 0 ? 126 : (which == 1 ? 125 : 124);
    float m = -1e30f;
    for (int l = 0; l < L; ++l) m = fmaxf(m, c[(size_t)(b * L + l) * 100 + f]);
    pool[b * 300 + which * 100 + f] = m;
}

// ---------------------------------------------------------------------------
// FIX (round 3): output is FLOAT32 (reference returns f32 softmax).
// ---------------------------------------------------------------------------
__global__ __launch_bounds__(128) void final_k(
    const float* __restrict__ pool,
    const u16* __restrict__ fc1W, const u16* __restrict__ fc1b,
    const u16* __restrict__ fc2W, const u16* __restrict__ fc2b,
    float* __restrict__ out)
{
    const int b = blockIdx.x, tid = threadIdx.x;
    __shared__ float ps[300], h1[100], lg[5];
    for (int d = tid; d < 300; d += 128) ps[d] = pool[b * 300 + d];
    __syncthreads();
    if (tid < 100) {
        float a = bf2f(fc1b[tid]);
        for (int k = 0; k < 300; ++k) a += bf2f(fc1W[tid * 300 + k]) * ps[k];
        h1[tid] = a;
    }
    __syncthreads();
    if (tid < 5) {
        float a = bf2f(fc2b[tid]);
        for (int k = 0; k < 100; ++k) a += bf2f(fc2W[tid * 100 + k]) * h1[k];
        lg[tid] = a;
    }
    __syncthreads();
    if (tid == 0) {
        float m = fmaxf(fmaxf(fmaxf(lg[0], lg[1]), fmaxf(lg[2], lg[3])), lg[4]);
        float e0 = __expf(lg[0] - m), e1 = __expf(lg[1] - m), e2 = __expf(lg[2] - m),
              e3 = __expf(lg[3] - m), e4 = __expf(lg[4] - m);
        float inv = 1.f / (e0 + e1 + e2 + e3 + e4);
        out[b * 5 + 0] = e0 * inv;
        out[b * 5 + 1] = e1 * inv;
        out[b * 5 + 2] = e2 * inv;
        out[b * 5 + 3] = e3 * inv;
        out[b * 5 + 4] = e4 * inv;
    }
}

// ---------------------------------------------------------------------------
extern "C" void kernel_launch(void* const* d_in, const int* in_sizes, int n_in,
                              void* d_out, int out_size, void* d_ws, size_t ws_size,
                              hipStream_t stream)
{
    (void)n_in; (void)out_size; (void)ws_size;

    const int*  inp     = (const int*)d_in[0];
    const void* embR    = d_in[1];
    const void* WxfR    = d_in[2];
    const void* WhfR    = d_in[3];
    const void* bxfR    = d_in[4];
    const void* bhfR    = d_in[5];
    const void* WxbR    = d_in[6];
    const void* WhbR    = d_in[7];
    const void* bxbR    = d_in[8];
    const void* bhbR    = d_in[9];
    const void* fc1cWR  = d_in[10];
    const void* fc1cbR  = d_in[11];
    const void* ctabR   = d_in[12];
    const void* cmaskR  = d_in[13];
    const void* cw0R    = d_in[14];
    const void* cb0R    = d_in[15];
    const void* cw1R    = d_in[16];
    const void* cb1R    = d_in[17];
    const void* cw2R    = d_in[18];
    const void* cb2R    = d_in[19];
    const void* fc1WR   = d_in[20];
    const void* fc1bR   = d_in[21];
    const void* fc2WR   = d_in[22];
    const void* fc2bR   = d_in[23];

    char* ws = (char*)d_ws;
    size_t off = 0;
    auto alloc = [&](size_t bytes) -> char* {
        char* r = ws + off;
        off = (off + bytes + 255) & ~(size_t)255;
        return r;
    };

    u16*   xgf    = (u16*)alloc(8192ull * 768 * 2);
    u16*   xgb    = (u16*)alloc(8192ull * 768 * 2);
    u32*   whtf   = (u32*)alloc(98304ull * 4);
    u32*   whtb   = (u32*)alloc(98304ull * 4);
    u16*   outb   = (u16*)alloc(8192ull * 512 * 2);
    u16*   feat   = (u16*)alloc(8192ull * 600 * 2);
    float* c0     = (float*)alloc(64ull * 126 * 100 * 4);
    float* c1     = (float*)alloc(64ull * 125 * 100 * 4);
    float* c2     = (float*)alloc(64ull * 124 * 100 * 4);
    float* pool   = (float*)alloc(64ull * 300 * 4);
    int*   flags  = (int*)alloc(256);
    int*   mask16 = (int*)alloc(30000ull * 4);
    u16*   embc   = (u16*)alloc(9000600ull * 2);
    u16*   wxfc   = (u16*)alloc(230400ull * 2);
    u16*   whfc   = (u16*)alloc(196608ull * 2);
    u16*   bxfc   = (u16*)alloc(768ull * 2);
    u16*   bhfc   = (u16*)alloc(768ull * 2);
    u16*   wxbc   = (u16*)alloc(230400ull * 2);
    u16*   whbc   = (u16*)alloc(196608ull * 2);
    u16*   bxbc   = (u16*)alloc(768ull * 2);
    u16*   bhbc   = (u16*)alloc(768ull * 2);
    u16*   fc1cWc = (u16*)alloc(153600ull * 2);
    u16*   fc1cbc = (u16*)alloc(300ull * 2);
    u16*   cw0c   = (u16*)alloc(180000ull * 2);
    u16*   cb0c   = (u16*)alloc(100ull * 2);
    u16*   cw1c   = (u16*)alloc(240000ull * 2);
    u16*   cb1c   = (u16*)alloc(100ull * 2);
    u16*   cw2c   = (u16*)alloc(300000ull * 2);
    u16*   cb2c   = (u16*)alloc(100ull * 2);
    u16*   fc1Wc  = (u16*)alloc(30000ull * 2);
    u16*   fc1bc  = (u16*)alloc(100ull * 2);
    u16*   fc2Wc  = (u16*)alloc(500ull * 2);
    u16*   fc2bc  = (u16*)alloc(8ull * 2);

    // 0) dtype detection
    detect_k<<<1, 256, 0, stream>>>((const u32*)embR, (const u32*)cmaskR, flags);

    // 1) convert/copy float weights to bf16 in ws
    {
        CvtArgs a{};
        a.d[0]  = { WxfR,   wxfc,   230400 };
        a.d[1]  = { WhfR,   whfc,   196608 };
        a.d[2]  = { bxfR,   bxfc,   768 };
        a.d[3]  = { bhfR,   bhfc,   768 };
        a.d[4]  = { WxbR,   wxbc,   230400 };
        a.d[5]  = { WhbR,   whbc,   196608 };
        a.d[6]  = { bxbR,   bxbc,   768 };
        a.d[7]  = { bhbR,   bhbc,   768 };
        a.d[8]  = { fc1cWR, fc1cWc, 153600 };
        a.d[9]  = { fc1cbR, fc1cbc, 300 };
        a.d[10] = { cw0R,   cw0c,   180000 };
        a.d[11] = { cb0R,   cb0c,   100 };
        a.d[12] = { cw1R,   cw1c,   240000 };
        a.d[13] = { cb1R,   cb1c,   100 };
        a.d[14] = { cw2R,   cw2c,   300000 };
        a.d[15] = { cb2R,   cb2c,   100 };
        a.d[16] = { fc1WR,  fc1Wc,  30000 };
        a.d[17] = { fc1bR,  fc1bc,  100 };
        a.d[18] = { fc2WR,  fc2Wc,  500 };
        a.d[19] = { fc2bR,  fc2bc,  5 };
        convert_many<<<dim3(293, 20), 256, 0, stream>>>(a, flags);
        CvtArgs e{};
        e.d[0] = { embR, embc, 9000600 };
        convert_many<<<dim3(8790, 1), 256, 0, stream>>>(e, flags);
    }

    // 2) concept mask -> bitmask
    build_mask<<<118, 256, 0, stream>>>(cmaskR, mask16, flags);

    // 3) pack/transpose Wh
    transpose_wh<<<dim3(384, 2), 256, 0, stream>>>(whfc, whbc, whtf, whtb);

    // 4) xg = emb[inp] @ Wx^T + bx
    gemm_bt<1, 1, 1><<<dim3(12, 128), 256, 0, stream>>>(
        embc, wxfc, bxfc, inp, nullptr, xgf, 8192, 768, 300, 300, 768, 0, 0);
    gemm_bt<1, 1, 1><<<dim3(12, 128), 256, 0, stream>>>(
        embc, wxbc, bxbc, inp, nullptr, xgb, 8192, 768, 300, 300, 768, 0, 0);

    // 5) bidirectional GRU scan -> outb [8192, 512]
    gru_scan<<<dim3(64, 2), 256, 0, stream>>>(xgf, xgb, whtf, whtb, bhfc, bhbc, outb);

    // 6) ctx = outb @ fc1c_W^T + b -> feat[:, 0:300]
    gemm_bt<0, 1, 1><<<dim3(5, 128), 256, 0, stream>>>(
        outb, fc1cWc, fc1cbc, nullptr, nullptr, feat, 8192, 300, 512, 512, 600, 0, 0);

    // 7) concept attention -> feat[:, 300:600]
    attn_kernel<<<dim3(8192), 256, 0, stream>>>(inp, ctabR, mask16, flags, feat);

    // 8) conv GEMMs over window views of feat (+bias, ReLU)
    gemm_bt<2, 2, 0><<<dim3(2, 126), 256, 0, stream>>>(
        feat, cw0c, cb0c, nullptr, c0, nullptr, 8064, 100, 1800, 600, 100, 126, 128);
    gemm_bt<2, 2, 0><<<dim3(2, 125), 256, 0, stream>>>(
        feat, cw1c, cb1c, nullptr, c1, nullptr, 8000, 100, 2400, 600, 100, 125, 128);
    gemm_bt<2, 2, 0><<<dim3(2, 124), 256, 0, stream>>>(
        feat, cw2c, cb2c, nullptr, c2, nullptr, 7936, 100, 3000, 600, 100, 124, 128);

    // 9) maxpool over positions
    maxpool_k<<<dim3(64, 3), 128, 0, stream>>>(c0, c1, c2, pool);

    // 10) fc1 -> fc2 -> softmax -> d_out (FLOAT32)
    final_k<<<dim3(64), 128, 0, stream>>>(pool, fc1Wc, fc1bc, fc2Wc, fc2bc, (float*)d_out);
}

// Round 4
// 593.978 us; speedup vs baseline: 2.1896x; 2.1896x over previous
//
#include <hip/hip_runtime.h>

// ---------------------------------------------------------------------------
// BiGRU + concept-attention + CNN classifier forward, MI355X gfx950.
// B=64 T=128 D=300 H=256 V=30000 K=16, filters 3/4/5 x100, CLS=5.
// Round 4: GRU scan rebuilt as register-resident-weight MFMA kernel.
//   - 16 blocks (8 batch-groups x 2 dirs) x 512 threads (8 waves).
//   - Each wave holds 48 B-fragments of Wh (192 VGPRs), preloaded once.
//   - Per step: LDS h (bf16) -> A-frags -> 48 MFMA -> gh LDS -> pointwise.
// Inputs f32 on device, output f32 (established round 2/3). Internals bf16.
// ---------------------------------------------------------------------------

typedef unsigned short u16;
typedef unsigned int u32;
typedef __attribute__((ext_vector_type(4))) u16 u16x4;
typedef __attribute__((ext_vector_type(8))) u16 u16x8;
typedef __attribute__((ext_vector_type(8))) __bf16 bf16x8;
typedef __attribute__((ext_vector_type(4))) float f32x4;

__device__ __forceinline__ float bf2f(u16 u) {
    union { u32 i; float f; } x; x.i = ((u32)u) << 16; return x.f;
}
__device__ __forceinline__ u16 f2bf(float f) {
    union { float f; u32 i; } x; x.f = f;
    u32 r = x.i + 0x7FFFu + ((x.i >> 16) & 1u);  // RNE
    return (u16)(r >> 16);
}
__device__ __forceinline__ float sigm(float x) { return 1.f / (1.f + __expf(-x)); }
__device__ __forceinline__ float tanh_(float x) {
    float e = __expf(-2.f * fabsf(x));
    float t = (1.f - e) / (1.f + e);
    return x < 0.f ? -t : t;
}

// ---------------------------------------------------------------------------
// detect_k: flags[0]=1 if float tensors are f32 (else bf16);
//           flags[1]=1 if concept_mask is byte-packed (else int32).
// ---------------------------------------------------------------------------
__global__ __launch_bounds__(256) void detect_k(
    const u32* __restrict__ emb_raw, const u32* __restrict__ cmask_raw,
    int* __restrict__ flags)
{
    __shared__ int cnt0, cnt1;
    if (threadIdx.x == 0) { cnt0 = 0; cnt1 = 0; }
    __syncthreads();
    int c0 = 0;
    for (int i = threadIdx.x; i < 4096; i += 256) {
        float lo = bf2f((u16)(emb_raw[i] & 0xFFFFu));
        if (!(fabsf(lo) <= 4.0f)) c0++;
    }
    int c1 = 0;
    for (int i = threadIdx.x; i < 1024; i += 256) {
        if (cmask_raw[i] > 1u) c1++;
    }
    if (c0) atomicAdd(&cnt0, c0);
    if (c1) atomicAdd(&cnt1, c1);
    __syncthreads();
    if (threadIdx.x == 0) {
        flags[0] = (cnt0 > 64) ? 1 : 0;
        flags[1] = (cnt1 > 0) ? 1 : 0;
    }
}

// ---------------------------------------------------------------------------
struct CvtDesc { const void* src; u16* dst; int n; };
struct CvtArgs { CvtDesc d[20]; };

__global__ __launch_bounds__(256) void convert_many(CvtArgs a, const int* __restrict__ flags)
{
    CvtDesc de = a.d[blockIdx.y];
    const bool f32m = flags[0] != 0;
    int i4 = (blockIdx.x * 256 + threadIdx.x) * 4;
    if (i4 >= de.n) return;
    if (i4 + 4 <= de.n) {
        if (f32m) {
            const float* s = (const float*)de.src + i4;
            u16x4 o; o[0] = f2bf(s[0]); o[1] = f2bf(s[1]); o[2] = f2bf(s[2]); o[3] = f2bf(s[3]);
            *(u16x4*)(de.dst + i4) = o;
        } else {
            *(u16x4*)(de.dst + i4) = *(const u16x4*)((const u16*)de.src + i4);
        }
    } else {
        for (int e = 0; e < 4 && i4 + e < de.n; ++e)
            de.dst[i4 + e] = f32m ? f2bf(((const float*)de.src)[i4 + e])
                                  : ((const u16*)de.src)[i4 + e];
    }
}

// ---------------------------------------------------------------------------
__global__ __launch_bounds__(256) void build_mask(
    const void* __restrict__ cmask, int* __restrict__ mask16, const int* __restrict__ flags)
{
    int v = blockIdx.x * 256 + threadIdx.x;
    if (v >= 30000) return;
    int m = 0;
    if (flags[1]) {
        const unsigned char* p = (const unsigned char*)cmask + (size_t)v * 16;
#pragma unroll
        for (int k = 0; k < 16; ++k) if (p[k]) m |= (1 << k);
    } else {
        const int* p = (const int*)cmask + (size_t)v * 16;
#pragma unroll
        for (int k = 0; k < 16; ++k) if (p[k]) m |= (1 << k);
    }
    mask16[v] = m;
}

// ---------------------------------------------------------------------------
// Generic MFMA GEMM (verified round 3). C[M,N] = A*W^T + bias (opt ReLU).
// ---------------------------------------------------------------------------
template<int ROWMODE, int EPI, int OUTBF>
__global__ __launch_bounds__(256) void gemm_bt(
    const u16* __restrict__ A, const u16* __restrict__ W,
    const u16* __restrict__ bias, const int* __restrict__ rowidx,
    float* __restrict__ Cf, u16* __restrict__ Cb,
    int M, int N, int K, int lda, int ldc, int Lrows, int strideT)
{
    __shared__ __align__(16) u16 sA[64 * 40];
    __shared__ __align__(16) u16 sW[64 * 40];

    const int tid = threadIdx.x;
    const int m0 = blockIdx.y * 64;
    const int n0 = blockIdx.x * 64;

    const int l  = tid & 63;
    const int w  = tid >> 6;
    const int wm = (w >> 1) << 5;
    const int wn = (w & 1) << 5;
    const int fr = l & 15;
    const int fk = (l >> 4) << 3;

    const int sr = tid >> 2;
    const int cb = (tid & 3) << 3;

    size_t abase;
    {
        int m = m0 + sr;
        if constexpr (ROWMODE == 1) {
            abase = (size_t)rowidx[m] * (size_t)lda;
        } else if constexpr (ROWMODE == 2) {
            int b = m / Lrows; int li = m - b * Lrows;
            abase = (size_t)(b * strideT + li) * (size_t)lda;
        } else {
            abase = (size_t)m * (size_t)lda;
        }
    }
    const int  wrow   = n0 + sr;
    const bool wvalid = wrow < N;
    const size_t wbase = (size_t)wrow * (size_t)K;

    f32x4 acc00 = {0,0,0,0}, acc01 = {0,0,0,0}, acc10 = {0,0,0,0}, acc11 = {0,0,0,0};

    for (int k0 = 0; k0 < K; k0 += 32) {
        __syncthreads();
        {
            u16x4 v0 = {0,0,0,0}, v1 = {0,0,0,0};
            int k = k0 + cb;
            if (k + 8 <= K) {
                const u16* p = A + abase + k;
                v0 = *(const u16x4*)p;
                v1 = *(const u16x4*)(p + 4);
            } else {
#pragma unroll
                for (int e = 0; e < 4; ++e) { int kk = k + e;     if (kk < K) v0[e] = A[abase + kk]; }
#pragma unroll
                for (int e = 0; e < 4; ++e) { int kk = k + 4 + e; if (kk < K) v1[e] = A[abase + kk]; }
            }
            *(u16x4*)(sA + sr * 40 + cb)     = v0;
            *(u16x4*)(sA + sr * 40 + cb + 4) = v1;
        }
        {
            u16x4 v0 = {0,0,0,0}, v1 = {0,0,0,0};
            int k = k0 + cb;
            if (wvalid) {
                if (k + 8 <= K) {
                    const u16* p = W + wbase + k;
                    v0 = *(const u16x4*)p;
                    v1 = *(const u16x4*)(p + 4);
                } else {
#pragma unroll
                    for (int e = 0; e < 4; ++e) { int kk = k + e;     if (kk < K) v0[e] = W[wbase + kk]; }
#pragma unroll
                    for (int e = 0; e < 4; ++e) { int kk = k + 4 + e; if (kk < K) v1[e] = W[wbase + kk]; }
                }
            }
            *(u16x4*)(sW + sr * 40 + cb)     = v0;
            *(u16x4*)(sW + sr * 40 + cb + 4) = v1;
        }
        __syncthreads();

        bf16x8 a0 = *(const bf16x8*)(sA + (wm + fr)      * 40 + fk);
        bf16x8 a1 = *(const bf16x8*)(sA + (wm + 16 + fr) * 40 + fk);
        bf16x8 b0 = *(const bf16x8*)(sW + (wn + fr)      * 40 + fk);
        bf16x8 b1 = *(const bf16x8*)(sW + (wn + 16 + fr) * 40 + fk);

        acc00 = __builtin_amdgcn_mfma_f32_16x16x32_bf16(a0, b0, acc00, 0, 0, 0);
        acc01 = __builtin_amdgcn_mfma_f32_16x16x32_bf16(a0, b1, acc01, 0, 0, 0);
        acc10 = __builtin_amdgcn_mfma_f32_16x16x32_bf16(a1, b0, acc10, 0, 0, 0);
        acc11 = __builtin_amdgcn_mfma_f32_16x16x32_bf16(a1, b1, acc11, 0, 0, 0);
    }

    const int rb = (l >> 4) << 2;
    const int cc = l & 15;
#define EPILOG(ACC, I, J)                                                     \
    {                                                                         \
        int col = n0 + wn + (J)*16 + cc;                                      \
        if (col < N) {                                                        \
            float bv = bf2f(bias[col]);                                       \
            _Pragma("unroll")                                                 \
            for (int r = 0; r < 4; ++r) {                                     \
                int row = m0 + wm + (I)*16 + rb + r;                          \
                if (row < M) {                                                \
                    float v = ACC[r] + bv;                                    \
                    if (EPI == 2) v = fmaxf(v, 0.f);                          \
                    if (OUTBF) Cb[(size_t)row * ldc + col] = f2bf(v);         \
                    else       Cf[(size_t)row * ldc + col] = v;               \
                }                                                             \
            }                                                                 \
        }                                                                     \
    }
    EPILOG(acc00, 0, 0); EPILOG(acc01, 0, 1); EPILOG(acc10, 1, 0); EPILOG(acc11, 1, 1);
#undef EPILOG
}

// ---------------------------------------------------------------------------
// GRU scan, MFMA + register-resident Wh.
// grid (8 batch-groups, 2 dirs) x 512 threads (8 waves).
// Wave w: (a) owns gate-output cols [w*96, w*96+96) in the GEMM phase,
//         (b) owns batch-row w in the pointwise phase.
// LDS: h as bf16 [16][264] (MFMA A source), h as f32 [8][260] (exact
// recurrence), gh [8][772] f32 (gate pre-activations), bh_s [768] f32.
// ---------------------------------------------------------------------------
#define GB 8   // batches per block
__global__ __launch_bounds__(512, 2) void gru_scan_mfma(
    const u16* __restrict__ xgf, const u16* __restrict__ xgb,
    const u16* __restrict__ whf, const u16* __restrict__ whb,
    const u16* __restrict__ bhf, const u16* __restrict__ bhb,
    u16* __restrict__ outb)
{
    const int bg  = blockIdx.x;
    const int dir = blockIdx.y;
    const u16* xg = dir ? xgb : xgf;
    const u16* wh = dir ? whb : whf;
    const u16* bh = dir ? bhb : bhf;

    const int tid = threadIdx.x;
    const int w = tid >> 6;      // wave id 0..7
    const int l = tid & 63;      // lane

    __shared__ __align__(16) u16 h_bf[16][264];   // rows 8..15 stay zero
    __shared__ __align__(16) float h_f[GB][260];
    __shared__ __align__(16) float gh[GB][772];
    __shared__ float bh_s[768];

    for (int i = tid; i < 16 * 264; i += 512) ((u16*)h_bf)[i] = 0;
    for (int i = tid; i < GB * 260; i += 512) ((float*)h_f)[i] = 0.f;
    for (int i = tid; i < 768; i += 512) bh_s[i] = bf2f(bh[i]);

    // --- preload B fragments: bfr[c][kt], lane l holds Wh[n][k..k+7]
    //     n = w*96 + c*16 + (l&15), k = kt*32 + (l>>4)*8   (layout verified
    //     by gemm_bt round-3 pass)
    bf16x8 bfr[6][8];
#pragma unroll
    for (int c = 0; c < 6; ++c) {
#pragma unroll
        for (int kt = 0; kt < 8; ++kt) {
            const int n = w * 96 + c * 16 + (l & 15);
            const int k = kt * 32 + (l >> 4) * 8;
            bfr[c][kt] = *(const bf16x8*)(wh + (size_t)n * 256 + k);
        }
    }

    const int qrow = (l >> 4) << 2;      // C-fragment row base
    const int arow = l & 15;             // A-fragment row
    const int aofs = (l >> 4) << 3;      // A-fragment k offset
    const int j0 = l * 4;                // pointwise: 4 hidden units per lane
    const int bglob = bg * GB + w;       // pointwise: global batch index

    __syncthreads();

    for (int s = 0; s < 128; ++s) {
        const int t = dir ? (127 - s) : s;

        // --- GEMM phase: gh[0:GB][0:768] = h @ Wh^T
        f32x4 acc[6];
#pragma unroll
        for (int c = 0; c < 6; ++c) acc[c] = (f32x4){0.f, 0.f, 0.f, 0.f};
#pragma unroll
        for (int kt = 0; kt < 8; ++kt) {
            bf16x8 a = *(const bf16x8*)(&h_bf[arow][kt * 32 + aofs]);
#pragma unroll
            for (int c = 0; c < 6; ++c)
                acc[c] = __builtin_amdgcn_mfma_f32_16x16x32_bf16(a, bfr[c][kt], acc[c], 0, 0, 0);
        }
        if (qrow < GB) {
#pragma unroll
            for (int c = 0; c < 6; ++c) {
                const int col = w * 96 + c * 16 + (l & 15);
#pragma unroll
                for (int r = 0; r < 4; ++r)
                    gh[qrow + r][col] = acc[c][r];
            }
        }
        __syncthreads();

        // --- pointwise phase: wave w = batch row w, lane l = j0..j0+3
        const size_t tokbase = (size_t)(bglob * 128 + t) * 768;
        u16x4 xr4 = *(const u16x4*)(xg + tokbase + j0);
        u16x4 xz4 = *(const u16x4*)(xg + tokbase + 256 + j0);
        u16x4 xn4 = *(const u16x4*)(xg + tokbase + 512 + j0);
        f32x4 gr = *(const f32x4*)(&gh[w][j0]);
        f32x4 gz = *(const f32x4*)(&gh[w][256 + j0]);
        f32x4 gn = *(const f32x4*)(&gh[w][512 + j0]);
        f32x4 br = *(const f32x4*)(&bh_s[j0]);
        f32x4 bz = *(const f32x4*)(&bh_s[256 + j0]);
        f32x4 bn = *(const f32x4*)(&bh_s[512 + j0]);
        f32x4 hp = *(const f32x4*)(&h_f[w][j0]);
        u16x4 ho;
        f32x4 hn;
#pragma unroll
        for (int e = 0; e < 4; ++e) {
            float r = sigm(bf2f(xr4[e]) + gr[e] + br[e]);
            float z = sigm(bf2f(xz4[e]) + gz[e] + bz[e]);
            float n = tanh_(bf2f(xn4[e]) + r * (gn[e] + bn[e]));
            float h2 = (1.f - z) * n + z * hp[e];
            hn[e] = h2;
            ho[e] = f2bf(h2);
        }
        *(u16x4*)(&h_bf[w][j0]) = ho;
        *(f32x4*)(&h_f[w][j0]) = hn;
        *(u16x4*)(outb + (size_t)(bglob * 128 + t) * 512 + dir * 256 + j0) = ho;
        __syncthreads();
    }
}
#undef GB

// ---------------------------------------------------------------------------
// Concept attention (unchanged, verified round 3).
// ---------------------------------------------------------------------------
__global__ __launch_bounds__(256) void attn_kernel(
    const int* __restrict__ inp, const void* __restrict__ ctab,
    const int* __restrict__ mask16, const int* __restrict__ flags,
    u16* __restrict__ feat)
{
    const int tok = blockIdx.x;
    const int tid = threadIdx.x;
    const int v = inp[tok];
    const bool f32m = flags[0] != 0;

    __shared__ float ctx_s[300];
    __shared__ __align__(16) u16 conc_s[16 * 300];
    __shared__ float sc_s[16];
    __shared__ float at_s[16];

    for (int d = tid; d < 300; d += 256) ctx_s[d] = bf2f(feat[(size_t)tok * 600 + d]);
    if (f32m) {
        const float4* src = (const float4*)((const float*)ctab + (size_t)v * 4800);
        for (int i = tid; i < 1200; i += 256) {
            float4 x = src[i];
            u16x4 o; o[0] = f2bf(x.x); o[1] = f2bf(x.y); o[2] = f2bf(x.z); o[3] = f2bf(x.w);
            *(u16x4*)(conc_s + i * 4) = o;
        }
    } else {
        const u16x8* src = (const u16x8*)((const u16*)ctab + (size_t)v * 4800);
        u16x8* dst = (u16x8*)conc_s;
        for (int i = tid; i < 600; i += 256) dst[i] = src[i];
    }
    __syncthreads();

    const int g = tid >> 4, ln = tid & 15;
    float s = 0.f;
    for (int d = ln; d < 300; d += 16) s += bf2f(conc_s[g * 300 + d]) * ctx_s[d];
    s += __shfl_xor(s, 1); s += __shfl_xor(s, 2); s += __shfl_xor(s, 4); s += __shfl_xor(s, 8);
    if (ln == 0) sc_s[g] = ((mask16[v] >> g) & 1) ? s : -1e30f;
    __syncthreads();

    if (tid == 0) {
        float m = -1e30f;
#pragma unroll
        for (int i = 0; i < 16; ++i) m = fmaxf(m, sc_s[i]);
        float p[16]; float den = 0.f;
#pragma unroll
        for (int i = 0; i < 16; ++i) {
            float pe = (sc_s[i] <= -1e29f) ? 0.f : __expf(sc_s[i] - m);
            p[i] = pe; den += pe;
        }
        float inv = den > 0.f ? 1.f / den : 0.f;
#pragma unroll
        for (int i = 0; i < 16; ++i) at_s[i] = p[i] * inv;
    }
    __syncthreads();

    for (int d = tid; d < 300; d += 256) {
        float a = 0.f;
#pragma unroll
        for (int g2 = 0; g2 < 16; ++g2) a += at_s[g2] * bf2f(conc_s[g2 * 300 + d]);
        feat[(size_t)tok * 600 + 300 + d] = f2bf(a);
    }
}

// ---------------------------------------------------------------------------
__global__ __launch_bounds__(128) void maxpool_k(
    const float* __restrict__ c0, const float* __restrict__ c1,
    const float* __restrict__ c2, float* __restrict__ pool)
{
    const int b = blockIdx.x, which = blockIdx.y, f = threadIdx.x;
    if (f >= 100) return;
    const float* c = which == 0 ? c0 : (which == 1 ? c1 : c2);
    const int L = which == 0 ? 126 : (which == 1 ? 125 : 124);
    float m = -1e30f;
    for (int l = 0; l < L; ++l) m = fmaxf(m, c[(size_t)(b * L + l) * 100 + f]);
    pool[b * 300 + which * 100 + f] = m;
}

// ---------------------------------------------------------------------------
__global__ __launch_bounds__(128) void final_k(
    const float* __restrict__ pool,
    const u16* __restrict__ fc1W, const u16* __restrict__ fc1b,
    const u16* __restrict__ fc2W, const u16* __restrict__ fc2b,
    float* __restrict__ out)
{
    const int b = blockIdx.x, tid = threadIdx.x;
    __shared__ float ps[300], h1[100], lg[5];
    for (int d = tid; d < 300; d += 128) ps[d] = pool[b * 300 + d];
    __syncthreads();
    if (tid < 100) {
        float a = bf2f(fc1b[tid]);
        for (int k = 0; k < 300; ++k) a += bf2f(fc1W[tid * 300 + k]) * ps[k];
        h1[tid] = a;
    }
    __syncthreads();
    if (tid < 5) {
        float a = bf2f(fc2b[tid]);
        for (int k = 0; k < 100; ++k) a += bf2f(fc2W[tid * 100 + k]) * h1[k];
        lg[tid] = a;
    }
    __syncthreads();
    if (tid == 0) {
        float m = fmaxf(fmaxf(fmaxf(lg[0], lg[1]), fmaxf(lg[2], lg[3])), lg[4]);
        float e0 = __expf(lg[0] - m), e1 = __expf(lg[1] - m), e2 = __expf(lg[2] - m),
              e3 = __expf(lg[3] - m), e4 = __expf(lg[4] - m);
        float inv = 1.f / (e0 + e1 + e2 + e3 + e4);
        out[b * 5 + 0] = e0 * inv;
        out[b * 5 + 1] = e1 * inv;
        out[b * 5 + 2] = e2 * inv;
        out[b * 5 + 3] = e3 * inv;
        out[b * 5 + 4] = e4 * inv;
    }
}

// ---------------------------------------------------------------------------
extern "C" void kernel_launch(void* const* d_in, const int* in_sizes, int n_in,
                              void* d_out, int out_size, void* d_ws, size_t ws_size,
                              hipStream_t stream)
{
    (void)n_in; (void)out_size; (void)ws_size;

    const int*  inp     = (const int*)d_in[0];
    const void* embR    = d_in[1];
    const void* WxfR    = d_in[2];
    const void* WhfR    = d_in[3];
    const void* bxfR    = d_in[4];
    const void* bhfR    = d_in[5];
    const void* WxbR    = d_in[6];
    const void* WhbR    = d_in[7];
    const void* bxbR    = d_in[8];
    const void* bhbR    = d_in[9];
    const void* fc1cWR  = d_in[10];
    const void* fc1cbR  = d_in[11];
    const void* ctabR   = d_in[12];
    const void* cmaskR  = d_in[13];
    const void* cw0R    = d_in[14];
    const void* cb0R    = d_in[15];
    const void* cw1R    = d_in[16];
    const void* cb1R    = d_in[17];
    const void* cw2R    = d_in[18];
    const void* cb2R    = d_in[19];
    const void* fc1WR   = d_in[20];
    const void* fc1bR   = d_in[21];
    const void* fc2WR   = d_in[22];
    const void* fc2bR   = d_in[23];

    char* ws = (char*)d_ws;
    size_t off = 0;
    auto alloc = [&](size_t bytes) -> char* {
        char* r = ws + off;
        off = (off + bytes + 255) & ~(size_t)255;
        return r;
    };

    u16*   xgf    = (u16*)alloc(8192ull * 768 * 2);
    u16*   xgb    = (u16*)alloc(8192ull * 768 * 2);
    u16*   outb   = (u16*)alloc(8192ull * 512 * 2);
    u16*   feat   = (u16*)alloc(8192ull * 600 * 2);
    float* c0     = (float*)alloc(64ull * 126 * 100 * 4);
    float* c1     = (float*)alloc(64ull * 125 * 100 * 4);
    float* c2     = (float*)alloc(64ull * 124 * 100 * 4);
    float* pool   = (float*)alloc(64ull * 300 * 4);
    int*   flags  = (int*)alloc(256);
    int*   mask16 = (int*)alloc(30000ull * 4);
    u16*   embc   = (u16*)alloc(9000600ull * 2);
    u16*   wxfc   = (u16*)alloc(230400ull * 2);
    u16*   whfc   = (u16*)alloc(196608ull * 2);
    u16*   bxfc   = (u16*)alloc(768ull * 2);
    u16*   bhfc   = (u16*)alloc(768ull * 2);
    u16*   wxbc   = (u16*)alloc(230400ull * 2);
    u16*   whbc   = (u16*)alloc(196608ull * 2);
    u16*   bxbc   = (u16*)alloc(768ull * 2);
    u16*   bhbc   = (u16*)alloc(768ull * 2);
    u16*   fc1cWc = (u16*)alloc(153600ull * 2);
    u16*   fc1cbc = (u16*)alloc(300ull * 2);
    u16*   cw0c   = (u16*)alloc(180000ull * 2);
    u16*   cb0c   = (u16*)alloc(100ull * 2);
    u16*   cw1c   = (u16*)alloc(240000ull * 2);
    u16*   cb1c   = (u16*)alloc(100ull * 2);
    u16*   cw2c   = (u16*)alloc(300000ull * 2);
    u16*   cb2c   = (u16*)alloc(100ull * 2);
    u16*   fc1Wc  = (u16*)alloc(30000ull * 2);
    u16*   fc1bc  = (u16*)alloc(100ull * 2);
    u16*   fc2Wc  = (u16*)alloc(500ull * 2);
    u16*   fc2bc  = (u16*)alloc(8ull * 2);

    // 0) dtype detection
    detect_k<<<1, 256, 0, stream>>>((const u32*)embR, (const u32*)cmaskR, flags);

    // 1) convert/copy float weights to bf16 in ws
    {
        CvtArgs a{};
        a.d[0]  = { WxfR,   wxfc,   230400 };
        a.d[1]  = { WhfR,   whfc,   196608 };
        a.d[2]  = { bxfR,   bxfc,   768 };
        a.d[3]  = { bhfR,   bhfc,   768 };
        a.d[4]  = { WxbR,   wxbc,   230400 };
        a.d[5]  = { WhbR,   whbc,   196608 };
        a.d[6]  = { bxbR,   bxbc,   768 };
        a.d[7]  = { bhbR,   bhbc,   768 };
        a.d[8]  = { fc1cWR, fc1cWc, 153600 };
        a.d[9]  = { fc1cbR, fc1cbc, 300 };
        a.d[10] = { cw0R,   cw0c,   180000 };
        a.d[11] = { cb0R,   cb0c,   100 };
        a.d[12] = { cw1R,   cw1c,   240000 };
        a.d[13] = { cb1R,   cb1c,   100 };
        a.d[14] = { cw2R,   cw2c,   300000 };
        a.d[15] = { cb2R,   cb2c,   100 };
        a.d[16] = { fc1WR,  fc1Wc,  30000 };
        a.d[17] = { fc1bR,  fc1bc,  100 };
        a.d[18] = { fc2WR,  fc2Wc,  500 };
        a.d[19] = { fc2bR,  fc2bc,  5 };
        convert_many<<<dim3(293, 20), 256, 0, stream>>>(a, flags);
        CvtArgs e{};
        e.d[0] = { embR, embc, 9000600 };
        convert_many<<<dim3(8790, 1), 256, 0, stream>>>(e, flags);
    }

    // 2) concept mask -> bitmask
    build_mask<<<118, 256, 0, stream>>>(cmaskR, mask16, flags);

    // 3) xg = emb[inp] @ Wx^T + bx
    gemm_bt<1, 1, 1><<<dim3(12, 128), 256, 0, stream>>>(
        embc, wxfc, bxfc, inp, nullptr, xgf, 8192, 768, 300, 300, 768, 0, 0);
    gemm_bt<1, 1, 1><<<dim3(12, 128), 256, 0, stream>>>(
        embc, wxbc, bxbc, inp, nullptr, xgb, 8192, 768, 300, 300, 768, 0, 0);

    // 4) bidirectional GRU scan (MFMA, register-resident Wh) -> outb
    gru_scan_mfma<<<dim3(8, 2), 512, 0, stream>>>(
        xgf, xgb, whfc, whbc, bhfc, bhbc, outb);

    // 5) ctx = outb @ fc1c_W^T + b -> feat[:, 0:300]
    gemm_bt<0, 1, 1><<<dim3(5, 128), 256, 0, stream>>>(
        outb, fc1cWc, fc1cbc, nullptr, nullptr, feat, 8192, 300, 512, 512, 600, 0, 0);

    // 6) concept attention -> feat[:, 300:600]
    attn_kernel<<<dim3(8192), 256, 0, stream>>>(inp, ctabR, mask16, flags, feat);

    // 7) conv GEMMs over window views of feat (+bias, ReLU)
    gemm_bt<2, 2, 0><<<dim3(2, 126), 256, 0, stream>>>(
        feat, cw0c, cb0c, nullptr, c0, nullptr, 8064, 100, 1800, 600, 100, 126, 128);
    gemm_bt<2, 2, 0><<<dim3(2, 125), 256, 0, stream>>>(
        feat, cw1c, cb1c, nullptr, c1, nullptr, 8000, 100, 2400, 600, 100, 125, 128);
    gemm_bt<2, 2, 0><<<dim3(2, 124), 256, 0, stream>>>(
        feat, cw2c, cb2c, nullptr, c2, nullptr, 7936, 100, 3000, 600, 100, 124, 128);

    // 8) maxpool over positions
    maxpool_k<<<dim3(64, 3), 128, 0, stream>>>(c0, c1, c2, pool);

    // 9) fc1 -> fc2 -> softmax -> d_out (f32)
    final_k<<<dim3(64), 128, 0, stream>>>(pool, fc1Wc, fc1bc, fc2Wc, fc2bc, (float*)d_out);
}